// Round 3
// baseline (388.899 us; speedup 1.0000x reference)
//
#include <hip/hip_runtime.h>
#include <cstdint>

typedef __attribute__((ext_vector_type(8))) short short8;
typedef __attribute__((ext_vector_type(4))) float f32x4;

#define NB 16
#define NT 2048
#define ND 1024
#define NC 512
#define NM (NB*NT)   // 32768 rows

#define BM 64        // rows per block
#define NWAVE 8      // 512 threads; wave w owns cols [w*64, w*64+64)

__device__ __forceinline__ unsigned short f2bf(float f){
  unsigned int u = __float_as_uint(f);
  u += 0x7fffu + ((u >> 16) & 1u);   // RNE; inputs are finite normals
  return (unsigned short)(u >> 16);
}

// ---------------- CAM GEMM + fused softmax, LDS-free ----------------
// No __shared__ staging, no barriers in the K-loop: every MFMA fragment is a
// direct 16B global load (A from L1 — 8x wave reuse; B streams from L2).
// Wave tile 64x64 = 4(mi) x 4(ni) of 16x16x32. acc 64 VGPR + 32 frag ≈ fits 128.
__global__ __launch_bounds__(512, 4) void cam_softmax_kernel(
    const unsigned short* __restrict__ Fb,   // bf16 [32768,1024]
    const unsigned short* __restrict__ Wb,   // bf16 [512,1024]
    float* __restrict__ out_soft,
    float* __restrict__ out_raw)
{
  __shared__ float redmax[NWAVE][BM];
  __shared__ float redsum[NWAVE][BM];

  const int tid    = threadIdx.x;
  const int wave   = tid >> 6;
  const int lane   = tid & 63;
  const int lane15 = lane & 15;
  const int quad   = lane >> 4;
  const int m0     = blockIdx.x * BM;

  f32x4 acc[4][4];
  #pragma unroll
  for (int mi = 0; mi < 4; mi++)
    #pragma unroll
    for (int ni = 0; ni < 4; ni++)
      acc[mi][ni] = (f32x4){0.f, 0.f, 0.f, 0.f};

  // Fragment base pointers: A[m=lane15(+16mi)][k=quad*8+j], B[n=lane15(+16ni)][k]
  const unsigned short* ap[4];
  const unsigned short* bp[4];
  #pragma unroll
  for (int mi = 0; mi < 4; mi++)
    ap[mi] = Fb + (size_t)(m0 + mi * 16 + lane15) * ND + quad * 8;
  #pragma unroll
  for (int ni = 0; ni < 4; ni++)
    bp[ni] = Wb + (size_t)(wave * 64 + ni * 16 + lane15) * ND + quad * 8;

  #pragma unroll 2
  for (int ks = 0; ks < ND / 32; ks++) {
    const int ko = ks * 32;
    short8 af[4], bf[4];
    #pragma unroll
    for (int mi = 0; mi < 4; mi++)
      af[mi] = *reinterpret_cast<const short8*>(ap[mi] + ko);
    #pragma unroll
    for (int ni = 0; ni < 4; ni++)
      bf[ni] = *reinterpret_cast<const short8*>(bp[ni] + ko);
    #pragma unroll
    for (int ni = 0; ni < 4; ni++)
      #pragma unroll
      for (int mi = 0; mi < 4; mi++)
        acc[mi][ni] = __builtin_amdgcn_mfma_f32_16x16x32_bf16(af[mi], bf[ni], acc[mi][ni], 0, 0, 0);
  }

  // ---- epilogue: fused softmax over C=512 ----
  // C/D layout: col = lane15 (+wave*64+ni*16), row = quad*4 + reg (+mi*16)
  #pragma unroll
  for (int mi = 0; mi < 4; mi++)
    #pragma unroll
    for (int r = 0; r < 4; r++) {
      float m = acc[mi][0][r];
      #pragma unroll
      for (int ni = 1; ni < 4; ni++) m = fmaxf(m, acc[mi][ni][r]);
      #pragma unroll
      for (int off = 1; off < 16; off <<= 1) m = fmaxf(m, __shfl_xor(m, off, 64));
      if (lane15 == 0) redmax[wave][mi * 16 + quad * 4 + r] = m;
    }
  __syncthreads();

  float rsum[4][4];
  #pragma unroll
  for (int mi = 0; mi < 4; mi++)
    #pragma unroll
    for (int r = 0; r < 4; r++) {
      const int row = mi * 16 + quad * 4 + r;
      float m = redmax[0][row];
      #pragma unroll
      for (int w = 1; w < NWAVE; w++) m = fmaxf(m, redmax[w][row]);
      float s = 0.f;
      #pragma unroll
      for (int ni = 0; ni < 4; ni++) {
        const float e = __expf(acc[mi][ni][r] - m);
        acc[mi][ni][r] = e;
        s += e;
      }
      #pragma unroll
      for (int off = 1; off < 16; off <<= 1) s += __shfl_xor(s, off, 64);
      rsum[mi][r] = s;
    }
  if (lane15 == 0) {
    #pragma unroll
    for (int mi = 0; mi < 4; mi++)
      #pragma unroll
      for (int r = 0; r < 4; r++)
        redsum[wave][mi * 16 + quad * 4 + r] = rsum[mi][r];
  }
  __syncthreads();

  #pragma unroll
  for (int mi = 0; mi < 4; mi++)
    #pragma unroll
    for (int r = 0; r < 4; r++) {
      const int row = mi * 16 + quad * 4 + r;
      float s = redsum[0][row];
      #pragma unroll
      for (int w = 1; w < NWAVE; w++) s += redsum[w][row];
      const float inv = 1.f / s;
      const size_t gr = (size_t)(m0 + row) * NC;
      #pragma unroll
      for (int ni = 0; ni < 4; ni++) {
        const int col = wave * 64 + ni * 16 + lane15;
        const float v = acc[mi][ni][r] * inv;
        out_soft[gr + col] = v;
        out_raw [gr + col] = v;
      }
    }
}

// ---------------- fused convert+pool: F fp32 -> Fb bf16, partial sums over T ----------------
// grid (32 zchunks, 16 b), 512 threads
__global__ __launch_bounds__(512) void convert_pool_kernel(
    const float* __restrict__ F, unsigned short* __restrict__ Fb,
    float* __restrict__ part)    // part[32][16][1024]
{
  __shared__ float4 psum[512];
  const int tid = threadIdx.x;
  const int z = blockIdx.x;
  const int b = blockIdx.y;
  const int th = tid >> 8;              // 0/1
  const int d4 = (tid & 255) * 4;

  float4 s = (float4){0.f, 0.f, 0.f, 0.f};
  const size_t base = ((size_t)b * NT + z * 64) * ND;
  #pragma unroll 4
  for (int t = th; t < 64; t += 2) {
    const size_t idx = base + (size_t)t * ND + d4;
    const float4 v = *reinterpret_cast<const float4*>(F + idx);
    ushort4 s4;
    s4.x = f2bf(v.x); s4.y = f2bf(v.y); s4.z = f2bf(v.z); s4.w = f2bf(v.w);
    *reinterpret_cast<ushort4*>(Fb + idx) = s4;
    s.x += v.x; s.y += v.y; s.z += v.z; s.w += v.w;
  }
  psum[tid] = s;
  __syncthreads();
  if (tid < 256) {
    const float4 a = psum[tid];
    const float4 c = psum[tid + 256];
    float4 r;
    r.x = a.x + c.x; r.y = a.y + c.y; r.z = a.z + c.z; r.w = a.w + c.w;
    *reinterpret_cast<float4*>(part + (size_t)(z * NB + b) * ND + d4) = r;
  }
}

// ---------------- W fp32 -> bf16 ----------------
__global__ __launch_bounds__(256) void convw_kernel(
    const float* __restrict__ W, unsigned short* __restrict__ Wb)
{
  const size_t j = ((size_t)blockIdx.x * 256 + threadIdx.x) * 8;
  const float4 a = *reinterpret_cast<const float4*>(W + j);
  const float4 c = *reinterpret_cast<const float4*>(W + j + 4);
  ushort4 lo, hi;
  lo.x = f2bf(a.x); lo.y = f2bf(a.y); lo.z = f2bf(a.z); lo.w = f2bf(a.w);
  hi.x = f2bf(c.x); hi.y = f2bf(c.y); hi.z = f2bf(c.z); hi.w = f2bf(c.w);
  *reinterpret_cast<ushort4*>(Wb + j) = lo;
  *reinterpret_cast<ushort4*>(Wb + j + 4) = hi;
}

// ---------------- logits = pooled @ W^T + b (fp32), grid (16 b, 8 colgroups) ----------------
__global__ __launch_bounds__(256) void logits_kernel(
    const float* __restrict__ part, const float* __restrict__ W,
    const float* __restrict__ bias, float* __restrict__ out_logits)
{
  __shared__ float p[ND];
  const int b   = blockIdx.x;
  const int cg  = blockIdx.y;
  const int tid = threadIdx.x;

  {  // pooled[b] into LDS (each thread: one float4 of D)
    const int d4 = tid * 4;
    float4 s = (float4){0.f, 0.f, 0.f, 0.f};
    #pragma unroll
    for (int z = 0; z < 32; z++) {
      const float4 v = *reinterpret_cast<const float4*>(part + (size_t)(z * NB + b) * ND + d4);
      s.x += v.x; s.y += v.y; s.z += v.z; s.w += v.w;
    }
    const float sc = 1.f / NT;
    p[d4] = s.x * sc; p[d4 + 1] = s.y * sc; p[d4 + 2] = s.z * sc; p[d4 + 3] = s.w * sc;
  }
  __syncthreads();

  // 64 cols per block, 4 threads per col (256 k each)
  const int col = cg * 64 + (tid >> 2);
  const int k0  = (tid & 3) * 256;
  const float* wr = W + (size_t)col * ND + k0;
  const float* pr = p + k0;
  float s = 0.f;
  #pragma unroll 8
  for (int j = 0; j < 256; j += 4) {
    const float4 w4 = *reinterpret_cast<const float4*>(wr + j);
    const float4 p4 = *reinterpret_cast<const float4*>(pr + j);
    s = fmaf(w4.x, p4.x, s); s = fmaf(w4.y, p4.y, s);
    s = fmaf(w4.z, p4.z, s); s = fmaf(w4.w, p4.w, s);
  }
  s += __shfl_xor(s, 1, 64);
  s += __shfl_xor(s, 2, 64);
  if ((tid & 3) == 0) out_logits[b * NC + col] = s + bias[col];
}

// ---------------- cross-entropy loss (fp32), one block, b parallel over waves ----------------
__global__ __launch_bounds__(512) void loss_kernel(
    const float* __restrict__ logits, const int* __restrict__ labels,
    float* __restrict__ out_loss)
{
  __shared__ float per_b[NB];
  const int tid  = threadIdx.x;
  const int wave = tid >> 6;
  const int lane = tid & 63;
  #pragma unroll
  for (int it = 0; it < 2; it++) {
    const int b = it * 8 + wave;
    const float* lg = logits + b * NC;
    const float4 v0 = *reinterpret_cast<const float4*>(lg + lane * 8);
    const float4 v1 = *reinterpret_cast<const float4*>(lg + lane * 8 + 4);
    float m = fmaxf(fmaxf(fmaxf(v0.x, v0.y), fmaxf(v0.z, v0.w)),
                    fmaxf(fmaxf(v1.x, v1.y), fmaxf(v1.z, v1.w)));
    #pragma unroll
    for (int off = 1; off < 64; off <<= 1) m = fmaxf(m, __shfl_xor(m, off, 64));
    float e = expf(v0.x - m) + expf(v0.y - m) + expf(v0.z - m) + expf(v0.w - m)
            + expf(v1.x - m) + expf(v1.y - m) + expf(v1.z - m) + expf(v1.w - m);
    #pragma unroll
    for (int off = 1; off < 64; off <<= 1) e += __shfl_xor(e, off, 64);
    if (lane == 0) {
      const int lab = labels[b];
      per_b[b] = -(lg[lab] - m - logf(e));
    }
  }
  __syncthreads();
  if (tid == 0) {
    float s = 0.f;
    #pragma unroll
    for (int i = 0; i < NB; i++) s += per_b[i];
    out_loss[0] = s * (1.f / NB);
  }
}

extern "C" void kernel_launch(void* const* d_in, const int* in_sizes, int n_in,
                              void* d_out, int out_size, void* d_ws, size_t ws_size,
                              hipStream_t stream) {
  const float* F      = (const float*)d_in[0];   // [16,2048,1024]
  const int*   labels = (const int*)  d_in[1];   // [16]
  const float* W      = (const float*)d_in[2];   // [512,1024]
  const float* bias   = (const float*)d_in[3];   // [512]

  float* out        = (float*)d_out;
  float* out_soft   = out;
  float* out_raw    = out + (size_t)NM * NC;
  float* out_logits = out + (size_t)2 * NM * NC;
  float* out_loss   = out_logits + (size_t)NB * NC;

  // ws layout: part [0, 2 MiB) | Wb [2 MiB, 3 MiB) | Fb [4 MiB, 68 MiB)
  // (ws_size is ~512 MiB per the harness poison fills — comfortably enough)
  char* ws = (char*)d_ws;
  float* part = (float*)ws;                                     // 32*16*1024 f32
  unsigned short* Wb = (unsigned short*)(ws + (2u << 20));      // 512*1024 bf16
  unsigned short* Fb = (unsigned short*)(ws + (4u << 20));      // 32768*1024 bf16

  convert_pool_kernel<<<dim3(32, NB), 512, 0, stream>>>(F, Fb, part);
  convw_kernel<<<NC * ND / (256 * 8), 256, 0, stream>>>(W, Wb);
  cam_softmax_kernel<<<NM / BM, 512, 0, stream>>>(Fb, Wb, out_soft, out_raw);
  logits_kernel<<<dim3(NB, 8), 256, 0, stream>>>(part, W, bias, out_logits);
  loss_kernel<<<1, 512, 0, stream>>>(out_logits, labels, out_loss);
}